// Round 6
// baseline (8400.284 us; speedup 1.0000x reference)
//
#include <hip/hip_runtime.h>

#define B_ 4
#define T_ 2048
#define CH 64

// ---------------------------------------------------------------------------
// Grid barrier (hand-rolled; 256 wgs are guaranteed co-resident since the
// kernel's 66KB LDS allows 2 wg/CU and grid == CU count). Device-scope
// atomics + __threadfence (fence seq_cst agent) handle cross-XCD L2
// non-coherence (G16).
// ---------------------------------------------------------------------------
__device__ __forceinline__ void gridbar(unsigned int* bar, int idx) {
  __syncthreads();   // drains this wg's vmem writes (compiler emits vmcnt(0))
  if (threadIdx.x == 0) {
    __hip_atomic_fetch_add(&bar[idx], 1u, __ATOMIC_ACQ_REL, __HIP_MEMORY_SCOPE_AGENT);
    while (__hip_atomic_load(&bar[idx], __ATOMIC_RELAXED, __HIP_MEMORY_SCOPE_AGENT) < 256u)
      __builtin_amdgcn_s_sleep(1);
    __threadfence();   // acquire: invalidate L1/L2 before post-barrier reads
  }
  __syncthreads();
}

// ---------------------------------------------------------------------------
// QKV projection (separate launch; fat grid benefits from multi-wg/CU).
// 128x128 tile, 8x8 micro, BK=8. grid (rows/128, 8, 3).
// ---------------------------------------------------------------------------
__global__ __launch_bounds__(256) void gemm_qkv(
    const float* __restrict__ X,
    const float* __restrict__ W0, const float* __restrict__ W1, const float* __restrict__ W2,
    float* __restrict__ O0, float* __restrict__ O1, float* __restrict__ O2,
    int tg, int lsh)
{
  const int z = blockIdx.z;
  const float* W = (z == 0) ? W0 : ((z == 1) ? W1 : W2);
  float* O = (z == 0) ? O0 : ((z == 1) ? O1 : O2);
  const float scale = (z == 0) ? 0.03125f : 1.0f;
  const int r0 = blockIdx.x * 128;
  const int c0 = blockIdx.y * 128;
  const int tid = threadIdx.x;
  const int tx = tid & 15, ty = tid >> 4;

  __shared__ float As[8][132];
  __shared__ float Bs[8][132];

  float acc[8][8] = {};
  const int ar = tid >> 1;
  const int ak = (tid & 1) * 4;
  const int bk = tid >> 5;
  const int bn = (tid & 31) * 4;

  const int lr = r0 + ar;
  const int grow = ((lr >> lsh) << 11) + tg + (lr & ((1 << lsh) - 1));

  for (int k0 = 0; k0 < 1024; k0 += 8) {
    float4 a4 = *reinterpret_cast<const float4*>(&X[grow * 1024 + k0 + ak]);
    float4 b4 = *reinterpret_cast<const float4*>(&W[(k0 + bk) * 1024 + c0 + bn]);
    __syncthreads();
    As[ak + 0][ar] = a4.x;
    As[ak + 1][ar] = a4.y;
    As[ak + 2][ar] = a4.z;
    As[ak + 3][ar] = a4.w;
    *reinterpret_cast<float4*>(&Bs[bk][bn]) = b4;
    __syncthreads();
#pragma unroll
    for (int kk = 0; kk < 8; ++kk) {
      float4 a0 = *reinterpret_cast<const float4*>(&As[kk][ty * 8]);
      float4 a1 = *reinterpret_cast<const float4*>(&As[kk][ty * 8 + 4]);
      float4 b0 = *reinterpret_cast<const float4*>(&Bs[kk][tx * 8]);
      float4 b1 = *reinterpret_cast<const float4*>(&Bs[kk][tx * 8 + 4]);
      float av[8] = {a0.x, a0.y, a0.z, a0.w, a1.x, a1.y, a1.z, a1.w};
      float bv[8] = {b0.x, b0.y, b0.z, b0.w, b1.x, b1.y, b1.z, b1.w};
#pragma unroll
      for (int i = 0; i < 8; ++i)
#pragma unroll
        for (int j = 0; j < 8; ++j) acc[i][j] += av[i] * bv[j];
    }
  }
#pragma unroll
  for (int i = 0; i < 8; ++i) {
    int row = r0 + ty * 8 + i;
#pragma unroll
    for (int j0 = 0; j0 < 8; j0 += 4) {
      float4 o = make_float4(acc[i][j0 + 0] * scale, acc[i][j0 + 1] * scale,
                             acc[i][j0 + 2] * scale, acc[i][j0 + 3] * scale);
      *reinterpret_cast<float4*>(&O[row * 1024 + c0 + tx * 8 + j0]) = o;
    }
  }
}

// ---------------------------------------------------------------------------
// Output projection (separate launch). 64x64 tiles, 4x4 micro, BK=16.
// ---------------------------------------------------------------------------
__global__ __launch_bounds__(256) void gemm_out(
    const float* __restrict__ Og, const float* __restrict__ Wo,
    float* __restrict__ out, int tg, int lsh)
{
  const int r0 = blockIdx.x * 64;
  const int c0 = blockIdx.y * 64;
  const int tid = threadIdx.x;
  const int tx = tid & 15, ty = tid >> 4;
  __shared__ float As[16][68];
  __shared__ float Bs[16][68];
  float acc[4][4] = {};
  const int ar = tid & 63;
  const int ak = (tid >> 6) * 4;
  const int bk = tid >> 4;
  const int bn = (tid & 15) * 4;

  for (int k0 = 0; k0 < 1024; k0 += 16) {
    float4 a4 = *reinterpret_cast<const float4*>(&Og[(r0 + ar) * 1024 + k0 + ak]);
    float4 b4 = *reinterpret_cast<const float4*>(&Wo[(k0 + bk) * 1024 + c0 + bn]);
    __syncthreads();
    As[ak + 0][ar] = a4.x;
    As[ak + 1][ar] = a4.y;
    As[ak + 2][ar] = a4.z;
    As[ak + 3][ar] = a4.w;
    *reinterpret_cast<float4*>(&Bs[bk][bn]) = b4;
    __syncthreads();
#pragma unroll
    for (int kk = 0; kk < 16; ++kk) {
      float4 av = *reinterpret_cast<const float4*>(&As[kk][ty * 4]);
      float4 bv = *reinterpret_cast<const float4*>(&Bs[kk][tx * 4]);
      float a[4] = {av.x, av.y, av.z, av.w};
      float b[4] = {bv.x, bv.y, bv.z, bv.w};
#pragma unroll
      for (int i = 0; i < 4; ++i)
#pragma unroll
        for (int j = 0; j < 4; ++j) acc[i][j] += a[i] * b[j];
    }
  }
#pragma unroll
  for (int i = 0; i < 4; ++i) {
    int lr = r0 + ty * 4 + i;
    int grow = ((lr >> lsh) << 11) + tg + (lr & ((1 << lsh) - 1));
    float4 o = make_float4(acc[i][0], acc[i][1], acc[i][2], acc[i][3]);
    *reinterpret_cast<float4*>(&out[grow * 1024 + c0 + tx * 4]) = o;
  }
}

// ---------------------------------------------------------------------------
// Persistent kernel: knorm -> attn(A,P) -> cpg x (rhsqs -> solve -> supdate).
// Grid fixed at 256 wgs x 256 threads. LDS = 66KB union => 2 wg/CU cap =>
// all 256 wgs co-resident; hand-rolled grid barriers between stages.
// ---------------------------------------------------------------------------
union SU {
  struct { float Rs[64][68], Cs[64][68]; } at;
  struct { float Ks[64][68], Qs[64][68], Ss[64][68]; } rh;
  struct { float RHS[64][68], QSl[64][68], Asm[64][64], Psm[64][64]; } so;
  struct { float Us[64][68], Ks[64][68]; } su;
  float knw[4];
};

__global__ __launch_bounds__(256) void mega_chain(
    const float* __restrict__ Qf, float* __restrict__ Kf,
    const float* __restrict__ Vf, float* __restrict__ Of,
    float* __restrict__ S, float* __restrict__ Ag, float* __restrict__ Pg,
    float* __restrict__ KSp, float* __restrict__ QSp, float* __restrict__ Ub,
    unsigned int* __restrict__ bar, int lsh, int cpg)
{
  const int wg = blockIdx.x;
  const int tid = threadIdx.x;
  const int tgs = 1 << lsh;
  const int rows = B_ << lsh;
  const int tx = tid & 15, ty = tid >> 4;
  int bidx = 0;

  __shared__ SU u;

  // ---- stage: knorm (rows x 1024, in place on Kf) ----
  for (int row = wg; row < rows; row += 256) {
    float4 v4 = *reinterpret_cast<const float4*>(&Kf[row * 1024 + tid * 4]);
    float ss = v4.x * v4.x + v4.y * v4.y + v4.z * v4.z + v4.w * v4.w;
#pragma unroll
    for (int off = 32; off > 0; off >>= 1) ss += __shfl_down(ss, off);
    __syncthreads();                       // protect knw reuse across rows
    if ((tid & 63) == 0) u.knw[tid >> 6] = ss;
    __syncthreads();
    float tot = u.knw[0] + u.knw[1] + u.knw[2] + u.knw[3];
    float inv = 1.0f / fmaxf(sqrtf(tot), 1e-12f);
    float4 o = make_float4(v4.x * inv, v4.y * inv, v4.z * inv, v4.w * inv);
    *reinterpret_cast<float4*>(&Kf[row * 1024 + tid * 4]) = o;
  }
  gridbar(bar, bidx++);

  // ---- stage: attn (A = strict-tril(KK^T), P = tril(QK^T)) ----
  for (int tile = wg; tile < 2 * B_ * cpg; tile += 256) {
    int z = tile / (B_ * cpg);
    int rem = tile % (B_ * cpg);
    int b = rem / cpg, cc = rem % cpg;
    int base = b * tgs + cc * CH;
    const float* R = z ? Qf : Kf;
    float acc[4][4] = {};
    for (int d0 = 0; d0 < 1024; d0 += 64) {
      __syncthreads();
#pragma unroll
      for (int i = 0; i < 4; ++i) {
        int qq = tid + i * 256;
        int t = qq >> 4, dq = (qq & 15) * 4;
        int gidx = (base + t) * 1024 + d0 + dq;
        *reinterpret_cast<float4*>(&u.at.Rs[t][dq]) = *reinterpret_cast<const float4*>(&R[gidx]);
        *reinterpret_cast<float4*>(&u.at.Cs[t][dq]) = *reinterpret_cast<const float4*>(&Kf[gidx]);
      }
      __syncthreads();
#pragma unroll
      for (int dd = 0; dd < 64; dd += 4) {
        float4 rv[4], cv[4];
#pragma unroll
        for (int a = 0; a < 4; ++a) rv[a] = *reinterpret_cast<const float4*>(&u.at.Rs[ty * 4 + a][dd]);
#pragma unroll
        for (int bb = 0; bb < 4; ++bb) cv[bb] = *reinterpret_cast<const float4*>(&u.at.Cs[tx * 4 + bb][dd]);
#pragma unroll
        for (int a = 0; a < 4; ++a)
#pragma unroll
          for (int bb = 0; bb < 4; ++bb)
            acc[a][bb] += rv[a].x * cv[bb].x + rv[a].y * cv[bb].y +
                          rv[a].z * cv[bb].z + rv[a].w * cv[bb].w;
      }
    }
    float* Out = z ? Pg : Ag;
#pragma unroll
    for (int a = 0; a < 4; ++a) {
      int t = ty * 4 + a;
      float4 o;
      int i0 = tx * 4;
      if (z == 0) {
        o.x = (i0 + 0 < t) ? acc[a][0] : 0.0f; o.y = (i0 + 1 < t) ? acc[a][1] : 0.0f;
        o.z = (i0 + 2 < t) ? acc[a][2] : 0.0f; o.w = (i0 + 3 < t) ? acc[a][3] : 0.0f;
      } else {
        o.x = (i0 + 0 <= t) ? acc[a][0] : 0.0f; o.y = (i0 + 1 <= t) ? acc[a][1] : 0.0f;
        o.z = (i0 + 2 <= t) ? acc[a][2] : 0.0f; o.w = (i0 + 3 <= t) ? acc[a][3] : 0.0f;
      }
      *reinterpret_cast<float4*>(&Out[((cc * B_ + b) * CH + t) * 64 + i0]) = o;
    }
  }
  gridbar(bar, bidx++);

  // ---- chain over chunks ----
  for (int cc = 0; cc < cpg; ++cc) {
    // --- rhsqs: wg -> (jt, ks, b); KS/QS partials over d-split of 256 ---
    {
      const int jt = wg & 15;
      const int ks = (wg >> 4) & 3;
      const int b = wg >> 6;
      const int j0 = jt * 64;
      const int base = b * tgs + cc * CH;
      float accK[4][4] = {};
      float accQ[4][4] = {};
      const int dbeg = ks * 256;
      for (int d0 = dbeg; d0 < dbeg + 256; d0 += 64) {
        __syncthreads();
#pragma unroll
        for (int i = 0; i < 4; ++i) {
          int qq = tid + i * 256;
          int t = qq >> 4, dq = (qq & 15) * 4;
          int gidx = (base + t) * 1024 + d0 + dq;
          *reinterpret_cast<float4*>(&u.rh.Ks[t][dq]) = *reinterpret_cast<const float4*>(&Kf[gidx]);
          *reinterpret_cast<float4*>(&u.rh.Qs[t][dq]) = *reinterpret_cast<const float4*>(&Qf[gidx]);
          *reinterpret_cast<float4*>(&u.rh.Ss[t][dq]) =
              *reinterpret_cast<const float4*>(&S[b * 1048576 + (j0 + t) * 1024 + d0 + dq]);
        }
        __syncthreads();
#pragma unroll
        for (int dd = 0; dd < 64; dd += 4) {
          float4 sv[4], kv[4], qv[4];
#pragma unroll
          for (int bb = 0; bb < 4; ++bb) sv[bb] = *reinterpret_cast<const float4*>(&u.rh.Ss[tx * 4 + bb][dd]);
#pragma unroll
          for (int a = 0; a < 4; ++a) {
            kv[a] = *reinterpret_cast<const float4*>(&u.rh.Ks[ty * 4 + a][dd]);
            qv[a] = *reinterpret_cast<const float4*>(&u.rh.Qs[ty * 4 + a][dd]);
          }
#pragma unroll
          for (int a = 0; a < 4; ++a)
#pragma unroll
            for (int bb = 0; bb < 4; ++bb) {
              accK[a][bb] += kv[a].x * sv[bb].x + kv[a].y * sv[bb].y +
                             kv[a].z * sv[bb].z + kv[a].w * sv[bb].w;
              accQ[a][bb] += qv[a].x * sv[bb].x + qv[a].y * sv[bb].y +
                             qv[a].z * sv[bb].z + qv[a].w * sv[bb].w;
            }
        }
      }
#pragma unroll
      for (int a = 0; a < 4; ++a) {
        int t = ty * 4 + a;
        int oidx = ((ks * B_ + b) * CH + t) * 1024 + j0 + tx * 4;
        *reinterpret_cast<float4*>(&KSp[oidx]) =
            make_float4(accK[a][0], accK[a][1], accK[a][2], accK[a][3]);
        *reinterpret_cast<float4*>(&QSp[oidx]) =
            make_float4(accQ[a][0], accQ[a][1], accQ[a][2], accQ[a][3]);
      }
    }
    gridbar(bar, bidx++);

    // --- solve: wgs 0..63 -> (cg, b) ---
    if (wg < 16 * B_) {
      const int cg = wg & 15;
      const int b = wg >> 4;
      const int col0 = cg * 64;
      const int base = b * tgs + cc * CH;
      const float* Ab = &Ag[((cc * B_ + b) * CH) * 64];
      const float* Pb = &Pg[((cc * B_ + b) * CH) * 64];
#pragma unroll
      for (int i = 0; i < 4; ++i) {
        int qq = tid + i * 256;
        int t = qq >> 4, c4 = (qq & 15) * 4;
        float4 r = *reinterpret_cast<const float4*>(&Vf[(base + t) * 1024 + col0 + c4]);
        float4 qs = make_float4(0.f, 0.f, 0.f, 0.f);
#pragma unroll
        for (int ks = 0; ks < 4; ++ks) {
          int pidx = ((ks * B_ + b) * CH + t) * 1024 + col0 + c4;
          float4 kp = *reinterpret_cast<const float4*>(&KSp[pidx]);
          float4 qp = *reinterpret_cast<const float4*>(&QSp[pidx]);
          r.x -= kp.x; r.y -= kp.y; r.z -= kp.z; r.w -= kp.w;
          qs.x += qp.x; qs.y += qp.y; qs.z += qp.z; qs.w += qp.w;
        }
        *reinterpret_cast<float4*>(&u.so.RHS[t][c4]) = r;
        *reinterpret_cast<float4*>(&u.so.QSl[t][c4]) = qs;
        *reinterpret_cast<float4*>(&u.so.Asm[t][c4]) = *reinterpret_cast<const float4*>(&Ab[t * 64 + c4]);
        *reinterpret_cast<float4*>(&u.so.Psm[t][c4]) = *reinterpret_cast<const float4*>(&Pb[t * 64 + c4]);
      }
      __syncthreads();

      if (tid < 64) {
        const int col = col0 + tid;
        float uu[64];
#pragma unroll
        for (int t = 0; t < 64; ++t) {
          float x = u.so.RHS[t][tid];
          float s0 = 0.f, s1 = 0.f, s2 = 0.f, s3 = 0.f;
          for (int i0 = 0; i0 + 4 <= t; i0 += 4) {
            float4 a4 = *reinterpret_cast<const float4*>(&u.so.Asm[t][i0]);
            s0 += a4.x * uu[i0 + 0]; s1 += a4.y * uu[i0 + 1];
            s2 += a4.z * uu[i0 + 2]; s3 += a4.w * uu[i0 + 3];
          }
          for (int i = (t >> 2) << 2; i < t; ++i) s0 += u.so.Asm[t][i] * uu[i];
          uu[t] = x - ((s0 + s1) + (s2 + s3));
        }
#pragma unroll
        for (int t = 0; t < 64; ++t) {
          float o = u.so.QSl[t][tid];
          float s0 = 0.f, s1 = 0.f, s2 = 0.f, s3 = 0.f;
          for (int i0 = 0; i0 + 4 <= t + 1; i0 += 4) {
            float4 p4 = *reinterpret_cast<const float4*>(&u.so.Psm[t][i0]);
            s0 += p4.x * uu[i0 + 0]; s1 += p4.y * uu[i0 + 1];
            s2 += p4.z * uu[i0 + 2]; s3 += p4.w * uu[i0 + 3];
          }
          for (int i = ((t + 1) >> 2) << 2; i <= t; ++i) s0 += u.so.Psm[t][i] * uu[i];
          o += (s0 + s1) + (s2 + s3);
          Ub[(b * CH + t) * 1024 + col] = uu[t];
          Of[(base + t) * 1024 + col] = o;
        }
      }
    }
    gridbar(bar, bidx++);

    // --- supdate: 1024 tiles over 256 wgs ---
    for (int tile = wg; tile < 256 * B_; tile += 256) {
      const int dt = tile & 15;
      const int jt = (tile >> 4) & 15;
      const int b = tile >> 8;
      const int d0 = dt * 64;
      const int j0 = jt * 64;
      const int base = b * tgs + cc * CH;
      __syncthreads();                      // protect LDS reuse across tiles
#pragma unroll
      for (int i = 0; i < 4; ++i) {
        int qq = tid + i * 256;
        int t = qq >> 4, xq = (qq & 15) * 4;
        *reinterpret_cast<float4*>(&u.su.Us[t][xq]) =
            *reinterpret_cast<const float4*>(&Ub[(b * CH + t) * 1024 + j0 + xq]);
        *reinterpret_cast<float4*>(&u.su.Ks[t][xq]) =
            *reinterpret_cast<const float4*>(&Kf[(base + t) * 1024 + d0 + xq]);
      }
      __syncthreads();
      float acc[4][4] = {};
#pragma unroll
      for (int t = 0; t < 64; ++t) {
        float4 u4 = *reinterpret_cast<const float4*>(&u.su.Us[t][ty * 4]);
        float4 k4 = *reinterpret_cast<const float4*>(&u.su.Ks[t][tx * 4]);
        float ua[4] = {u4.x, u4.y, u4.z, u4.w};
        float kb[4] = {k4.x, k4.y, k4.z, k4.w};
#pragma unroll
        for (int a = 0; a < 4; ++a)
#pragma unroll
          for (int bb = 0; bb < 4; ++bb) acc[a][bb] += ua[a] * kb[bb];
      }
#pragma unroll
      for (int a = 0; a < 4; ++a) {
        int idx = b * 1048576 + (j0 + ty * 4 + a) * 1024 + d0 + tx * 4;
        float4 s4 = *reinterpret_cast<float4*>(&S[idx]);
        s4.x += acc[a][0]; s4.y += acc[a][1]; s4.z += acc[a][2]; s4.w += acc[a][3];
        *reinterpret_cast<float4*>(&S[idx]) = s4;
      }
    }
    gridbar(bar, bidx++);
  }
}

// ---------------------------------------------------------------------------
extern "C" void kernel_launch(void* const* d_in, const int* in_sizes, int n_in,
                              void* d_out, int out_size, void* d_ws, size_t ws_size,
                              hipStream_t stream) {
  const float* x  = (const float*)d_in[0];
  const float* Wq = (const float*)d_in[1];
  const float* Wk = (const float*)d_in[2];
  const float* Wv = (const float*)d_in[3];
  const float* Wo = (const float*)d_in[4];
  float* out = (float*)d_out;

  // tier: largest time-group that fits ws
  int lsh = 8;
  {
    const int cand[4] = {11, 10, 9, 8};
    for (int i = 0; i < 4; ++i) {
      size_t tgs = (size_t)1 << cand[i];
      size_t cpg = tgs / CH;
      size_t need = 4 * (B_ * tgs * 1024 * 4)             // Q,K,V,O
                  + (size_t)B_ * 1024 * 1024 * 4          // S
                  + 8192                                  // bar
                  + 2 * (cpg * B_ * CH * 64 * 4)          // A,P
                  + 2 * ((size_t)4 * B_ * CH * 1024 * 4)  // KSp,QSp
                  + (size_t)B_ * CH * 1024 * 4            // U
                  + 16384;
      if (need <= ws_size) { lsh = cand[i]; break; }
    }
  }
  const int tgs = 1 << lsh;
  const int cpg = tgs / CH;
  const int ngrp = T_ / tgs;
  const int rows = B_ * tgs;
  const int nbarpg = 2 + 3 * cpg;

  char* ws = (char*)d_ws;
  size_t off = 0;
  auto alloc = [&](size_t bytes) -> void* {
    void* p = ws + off;
    off += (bytes + 255) & ~(size_t)255;
    return p;
  };
  float* Qg = (float*)alloc((size_t)rows * 1024 * 4);
  float* Kg = (float*)alloc((size_t)rows * 1024 * 4);
  float* Vg = (float*)alloc((size_t)rows * 1024 * 4);
  float* Og = (float*)alloc((size_t)rows * 1024 * 4);
  float* S  = (float*)alloc((size_t)B_ * 1024 * 1024 * 4);
  unsigned int* bar = (unsigned int*)alloc(8192);   // directly after S
  float* Ag  = (float*)alloc((size_t)cpg * B_ * CH * 64 * 4);
  float* Pg  = (float*)alloc((size_t)cpg * B_ * CH * 64 * 4);
  float* KSp = (float*)alloc((size_t)4 * B_ * CH * 1024 * 4);
  float* QSp = (float*)alloc((size_t)4 * B_ * CH * 1024 * 4);
  float* Ub  = (float*)alloc((size_t)B_ * CH * 1024 * 4);

  // zero S and all barrier counters in one shot (contiguous)
  (void)hipMemsetAsync(S, 0, (size_t)B_ * 1024 * 1024 * 4 + 8192, stream);

  for (int g = 0; g < ngrp; ++g) {
    int tg = g * tgs;
    gemm_qkv<<<dim3(rows / 128, 8, 3), 256, 0, stream>>>(x, Wq, Wk, Wv, Qg, Kg, Vg, tg, lsh);
    mega_chain<<<256, 256, 0, stream>>>(Qg, Kg, Vg, Og, S, Ag, Pg, KSp, QSp, Ub,
                                        bar + g * nbarpg, lsh, cpg);
    gemm_out<<<dim3(rows / 64, 16), 256, 0, stream>>>(Og, Wo, out, tg, lsh);
  }
}

// Round 7
// 5306.832 us; speedup vs baseline: 1.5829x; 1.5829x over previous
//
#include <hip/hip_runtime.h>

#define B_ 4
#define T_ 2048
#define CH 64
#define NSL 64        // DV column-slices per batch
#define SLW 16        // columns per slice (NSL*SLW = 1024 = DV)

// ---------------------------------------------------------------------------
// QKV projection. 128x128 tile, 8x8 micro, BK=8. grid (rows/128, 8, 3).
// ---------------------------------------------------------------------------
__global__ __launch_bounds__(256) void gemm_qkv(
    const float* __restrict__ X,
    const float* __restrict__ W0, const float* __restrict__ W1, const float* __restrict__ W2,
    float* __restrict__ O0, float* __restrict__ O1, float* __restrict__ O2,
    int tg, int lsh)
{
  const int z = blockIdx.z;
  const float* W = (z == 0) ? W0 : ((z == 1) ? W1 : W2);
  float* O = (z == 0) ? O0 : ((z == 1) ? O1 : O2);
  const float scale = (z == 0) ? 0.03125f : 1.0f;
  const int r0 = blockIdx.x * 128;
  const int c0 = blockIdx.y * 128;
  const int tid = threadIdx.x;
  const int tx = tid & 15, ty = tid >> 4;

  __shared__ float As[8][132];
  __shared__ float Bs[8][132];

  float acc[8][8] = {};
  const int ar = tid >> 1;
  const int ak = (tid & 1) * 4;
  const int bk = tid >> 5;
  const int bn = (tid & 31) * 4;

  const int lr = r0 + ar;
  const int grow = ((lr >> lsh) << 11) + tg + (lr & ((1 << lsh) - 1));

  for (int k0 = 0; k0 < 1024; k0 += 8) {
    float4 a4 = *reinterpret_cast<const float4*>(&X[grow * 1024 + k0 + ak]);
    float4 b4 = *reinterpret_cast<const float4*>(&W[(k0 + bk) * 1024 + c0 + bn]);
    __syncthreads();
    As[ak + 0][ar] = a4.x;
    As[ak + 1][ar] = a4.y;
    As[ak + 2][ar] = a4.z;
    As[ak + 3][ar] = a4.w;
    *reinterpret_cast<float4*>(&Bs[bk][bn]) = b4;
    __syncthreads();
#pragma unroll
    for (int kk = 0; kk < 8; ++kk) {
      float4 a0 = *reinterpret_cast<const float4*>(&As[kk][ty * 8]);
      float4 a1 = *reinterpret_cast<const float4*>(&As[kk][ty * 8 + 4]);
      float4 b0 = *reinterpret_cast<const float4*>(&Bs[kk][tx * 8]);
      float4 b1 = *reinterpret_cast<const float4*>(&Bs[kk][tx * 8 + 4]);
      float av[8] = {a0.x, a0.y, a0.z, a0.w, a1.x, a1.y, a1.z, a1.w};
      float bv[8] = {b0.x, b0.y, b0.z, b0.w, b1.x, b1.y, b1.z, b1.w};
#pragma unroll
      for (int i = 0; i < 8; ++i)
#pragma unroll
        for (int j = 0; j < 8; ++j) acc[i][j] += av[i] * bv[j];
    }
  }
#pragma unroll
  for (int i = 0; i < 8; ++i) {
    int row = r0 + ty * 8 + i;
#pragma unroll
    for (int j0 = 0; j0 < 8; j0 += 4) {
      float4 o = make_float4(acc[i][j0 + 0] * scale, acc[i][j0 + 1] * scale,
                             acc[i][j0 + 2] * scale, acc[i][j0 + 3] * scale);
      *reinterpret_cast<float4*>(&O[row * 1024 + c0 + tx * 8 + j0]) = o;
    }
  }
}

// ---------------------------------------------------------------------------
// Output projection, same 128-tile shape. grid (rows/128, 8).
// ---------------------------------------------------------------------------
__global__ __launch_bounds__(256) void gemm_out(
    const float* __restrict__ Og, const float* __restrict__ Wo,
    float* __restrict__ out, int tg, int lsh)
{
  const int r0 = blockIdx.x * 128;
  const int c0 = blockIdx.y * 128;
  const int tid = threadIdx.x;
  const int tx = tid & 15, ty = tid >> 4;

  __shared__ float As[8][132];
  __shared__ float Bs[8][132];

  float acc[8][8] = {};
  const int ar = tid >> 1;
  const int ak = (tid & 1) * 4;
  const int bk = tid >> 5;
  const int bn = (tid & 31) * 4;

  for (int k0 = 0; k0 < 1024; k0 += 8) {
    float4 a4 = *reinterpret_cast<const float4*>(&Og[(r0 + ar) * 1024 + k0 + ak]);
    float4 b4 = *reinterpret_cast<const float4*>(&Wo[(k0 + bk) * 1024 + c0 + bn]);
    __syncthreads();
    As[ak + 0][ar] = a4.x;
    As[ak + 1][ar] = a4.y;
    As[ak + 2][ar] = a4.z;
    As[ak + 3][ar] = a4.w;
    *reinterpret_cast<float4*>(&Bs[bk][bn]) = b4;
    __syncthreads();
#pragma unroll
    for (int kk = 0; kk < 8; ++kk) {
      float4 a0 = *reinterpret_cast<const float4*>(&As[kk][ty * 8]);
      float4 a1 = *reinterpret_cast<const float4*>(&As[kk][ty * 8 + 4]);
      float4 b0 = *reinterpret_cast<const float4*>(&Bs[kk][tx * 8]);
      float4 b1 = *reinterpret_cast<const float4*>(&Bs[kk][tx * 8 + 4]);
      float av[8] = {a0.x, a0.y, a0.z, a0.w, a1.x, a1.y, a1.z, a1.w};
      float bv[8] = {b0.x, b0.y, b0.z, b0.w, b1.x, b1.y, b1.z, b1.w};
#pragma unroll
      for (int i = 0; i < 8; ++i)
#pragma unroll
        for (int j = 0; j < 8; ++j) acc[i][j] += av[i] * bv[j];
    }
  }
#pragma unroll
  for (int i = 0; i < 8; ++i) {
    int lr = r0 + ty * 8 + i;
    int grow = ((lr >> lsh) << 11) + tg + (lr & ((1 << lsh) - 1));
#pragma unroll
    for (int j0 = 0; j0 < 8; j0 += 4) {
      float4 o = make_float4(acc[i][j0], acc[i][j0 + 1], acc[i][j0 + 2], acc[i][j0 + 3]);
      *reinterpret_cast<float4*>(&out[grow * 1024 + c0 + tx * 8 + j0]) = o;
    }
  }
}

// ---------------------------------------------------------------------------
// Row-normalize Kg (rows x 1024)
// ---------------------------------------------------------------------------
__global__ __launch_bounds__(256) void knorm_kernel(float* __restrict__ K) {
  const int row = blockIdx.x;
  const int tid = threadIdx.x;
  float4 v4 = *reinterpret_cast<const float4*>(&K[row * 1024 + tid * 4]);
  float ss = v4.x * v4.x + v4.y * v4.y + v4.z * v4.z + v4.w * v4.w;
#pragma unroll
  for (int off = 32; off > 0; off >>= 1) ss += __shfl_down(ss, off);
  __shared__ float wsum[4];
  if ((tid & 63) == 0) wsum[tid >> 6] = ss;
  __syncthreads();
  float tot = wsum[0] + wsum[1] + wsum[2] + wsum[3];
  float inv = 1.0f / fmaxf(sqrtf(tot), 1e-12f);
  float4 o = make_float4(v4.x * inv, v4.y * inv, v4.z * inv, v4.w * inv);
  *reinterpret_cast<float4*>(&K[row * 1024 + tid * 4]) = o;
}

// ---------------------------------------------------------------------------
// A/P precompute. z=0: A=strict-tril(KK^T); z=1: P=tril(QK^T). grid (2,B_,cpg)
// ---------------------------------------------------------------------------
__global__ __launch_bounds__(256) void attn_all_kernel(
    const float* __restrict__ Q, const float* __restrict__ K,
    float* __restrict__ Ag, float* __restrict__ Pg, int tgs)
{
  const int z = blockIdx.x;
  const int b = blockIdx.y;
  const int cc = blockIdx.z;
  const int base = b * tgs + cc * CH;
  const float* R = z ? Q : K;
  const int tid = threadIdx.x;
  const int tx = tid & 15, ty = tid >> 4;
  __shared__ float Rs[64][68];
  __shared__ float Cs[64][68];
  float acc[4][4] = {};
  for (int d0 = 0; d0 < 1024; d0 += 64) {
    __syncthreads();
#pragma unroll
    for (int i = 0; i < 4; ++i) {
      int qq = tid + i * 256;
      int t = qq >> 4, dq = (qq & 15) * 4;
      int gidx = (base + t) * 1024 + d0 + dq;
      *reinterpret_cast<float4*>(&Rs[t][dq]) = *reinterpret_cast<const float4*>(&R[gidx]);
      *reinterpret_cast<float4*>(&Cs[t][dq]) = *reinterpret_cast<const float4*>(&K[gidx]);
    }
    __syncthreads();
#pragma unroll
    for (int dd = 0; dd < 64; dd += 4) {
      float4 rv[4], cv[4];
#pragma unroll
      for (int a = 0; a < 4; ++a) rv[a] = *reinterpret_cast<const float4*>(&Rs[ty * 4 + a][dd]);
#pragma unroll
      for (int bb = 0; bb < 4; ++bb) cv[bb] = *reinterpret_cast<const float4*>(&Cs[tx * 4 + bb][dd]);
#pragma unroll
      for (int a = 0; a < 4; ++a)
#pragma unroll
        for (int bb = 0; bb < 4; ++bb)
          acc[a][bb] += rv[a].x * cv[bb].x + rv[a].y * cv[bb].y +
                        rv[a].z * cv[bb].z + rv[a].w * cv[bb].w;
    }
  }
  float* Out = z ? Pg : Ag;
#pragma unroll
  for (int a = 0; a < 4; ++a) {
    int t = ty * 4 + a;
    float4 o;
    int i0 = tx * 4;
    if (z == 0) {
      o.x = (i0 + 0 < t) ? acc[a][0] : 0.0f; o.y = (i0 + 1 < t) ? acc[a][1] : 0.0f;
      o.z = (i0 + 2 < t) ? acc[a][2] : 0.0f; o.w = (i0 + 3 < t) ? acc[a][3] : 0.0f;
    } else {
      o.x = (i0 + 0 <= t) ? acc[a][0] : 0.0f; o.y = (i0 + 1 <= t) ? acc[a][1] : 0.0f;
      o.z = (i0 + 2 <= t) ? acc[a][2] : 0.0f; o.w = (i0 + 3 <= t) ? acc[a][3] : 0.0f;
    }
    *reinterpret_cast<float4*>(&Out[((cc * B_ + b) * CH + t) * 64 + i0]) = o;
  }
}

// ---------------------------------------------------------------------------
// Persistent-state chain. 256 wgs; wg = b*NSL + sl owns S[c0:c0+16][0:1024]
// in LDS for the whole kernel. Per chunk (sequential, NO inter-wg sync):
//   phase A: KS[t][c] = K_t . S_c ; QS[t][c] = Q_t . S_c   (full d)
//   phase B: forward-subst (I+A)u = V-KS; o = QS + P u  (column-local)
//   phase C: S_c += sum_t u[t][c] * K_t                  (rows c only)
// Cross-group state via Sglob when ngrp > 1.
// ---------------------------------------------------------------------------
__global__ __launch_bounds__(256) void chain_kernel(
    const float* __restrict__ Qf, const float* __restrict__ Kf,
    const float* __restrict__ Vf, float* __restrict__ Of,
    const float* __restrict__ Ag, const float* __restrict__ Pg,
    float* __restrict__ Sglob, int lsh, int cpg, int g, int ngrp)
{
  const int wg = blockIdx.x;
  const int b = wg >> 6;
  const int sl = wg & 63;
  const int c0 = sl * SLW;
  const int tgs = 1 << lsh;
  const int tid = threadIdx.x;
  const int c = tid & 15;        // column within slice (phase A)
  const int tg = tid >> 4;       // t-group (phase A)

  __shared__ float Ssl[SLW][1028];   // persistent S slice (stride 1028: 2-way max)
  __shared__ float Ksm[64][68];
  __shared__ float Qsm[64][68];
  __shared__ float Asm[64][64];
  __shared__ float Psm[64][64];
  __shared__ float uT[SLW][68];      // u transposed [c][t]
  __shared__ float rhs[64][SLW];
  __shared__ float qsa[64][SLW];

  // init S slice
  if (g == 0) {
#pragma unroll
    for (int i = 0; i < 16; ++i) {
      int idx = tid + i * 256;               // 0..4095 covers 16x1024/4
      int r = idx >> 8, d4 = (idx & 255) * 4;
      *reinterpret_cast<float4*>(&Ssl[r][d4]) = make_float4(0.f, 0.f, 0.f, 0.f);
    }
  } else {
#pragma unroll
    for (int i = 0; i < 16; ++i) {
      int idx = tid + i * 256;
      int r = idx >> 8, d4 = (idx & 255) * 4;
      *reinterpret_cast<float4*>(&Ssl[r][d4]) =
          *reinterpret_cast<const float4*>(&Sglob[((size_t)b * 1024 + c0 + r) * 1024 + d4]);
    }
  }
  __syncthreads();

  for (int cc = 0; cc < cpg; ++cc) {
    const int base = b * tgs + cc * CH;
    const int abase = ((cc * B_ + b) * CH) * 64;

    // ---- phase A: KS/QS over full d ----
    float accK[4] = {0.f, 0.f, 0.f, 0.f};
    float accQ[4] = {0.f, 0.f, 0.f, 0.f};
    for (int d0 = 0; d0 < 1024; d0 += 64) {
      __syncthreads();
#pragma unroll
      for (int i = 0; i < 4; ++i) {
        int idx = tid + i * 256;
        int row = idx >> 4, d4 = (idx & 15) * 4;
        *reinterpret_cast<float4*>(&Ksm[row][d4]) =
            *reinterpret_cast<const float4*>(&Kf[(base + row) * 1024 + d0 + d4]);
        *reinterpret_cast<float4*>(&Qsm[row][d4]) =
            *reinterpret_cast<const float4*>(&Qf[(base + row) * 1024 + d0 + d4]);
      }
      __syncthreads();
#pragma unroll
      for (int dd = 0; dd < 64; dd += 4) {
        float4 s4 = *reinterpret_cast<const float4*>(&Ssl[c][d0 + dd]);
#pragma unroll
        for (int r = 0; r < 4; ++r) {
          float4 k4 = *reinterpret_cast<const float4*>(&Ksm[tg * 4 + r][dd]);
          float4 q4 = *reinterpret_cast<const float4*>(&Qsm[tg * 4 + r][dd]);
          accK[r] += k4.x * s4.x + k4.y * s4.y + k4.z * s4.z + k4.w * s4.w;
          accQ[r] += q4.x * s4.x + q4.y * s4.y + q4.z * s4.z + q4.w * s4.w;
        }
      }
    }
    // rhs = V - KS ; qsa = QS ; stage A,P
#pragma unroll
    for (int r = 0; r < 4; ++r) {
      int t = tg * 4 + r;
      rhs[t][c] = Vf[(base + t) * 1024 + c0 + c] - accK[r];
      qsa[t][c] = accQ[r];
    }
#pragma unroll
    for (int i = 0; i < 4; ++i) {
      int idx = tid + i * 256;
      int row = idx >> 4, i4 = (idx & 15) * 4;
      *reinterpret_cast<float4*>(&Asm[row][i4]) =
          *reinterpret_cast<const float4*>(&Ag[abase + row * 64 + i4]);
      *reinterpret_cast<float4*>(&Psm[row][i4]) =
          *reinterpret_cast<const float4*>(&Pg[abase + row * 64 + i4]);
    }
    __syncthreads();

    // ---- phase B: column-local triangular solve + output ----
    if (tid < SLW) {
      const int cB = tid;
      float uu[64];
#pragma unroll
      for (int t = 0; t < 64; ++t) {
        float x = rhs[t][cB];
        float s0 = 0.f, s1 = 0.f, s2 = 0.f, s3 = 0.f;
        for (int i0 = 0; i0 + 4 <= t; i0 += 4) {
          float4 a4 = *reinterpret_cast<const float4*>(&Asm[t][i0]);
          s0 += a4.x * uu[i0 + 0]; s1 += a4.y * uu[i0 + 1];
          s2 += a4.z * uu[i0 + 2]; s3 += a4.w * uu[i0 + 3];
        }
        for (int i = (t >> 2) << 2; i < t; ++i) s0 += Asm[t][i] * uu[i];
        uu[t] = x - ((s0 + s1) + (s2 + s3));
        uT[cB][t] = uu[t];
      }
#pragma unroll
      for (int t = 0; t < 64; ++t) {
        float o = qsa[t][cB];
        float s0 = 0.f, s1 = 0.f, s2 = 0.f, s3 = 0.f;
        for (int i0 = 0; i0 + 4 <= t + 1; i0 += 4) {
          float4 p4 = *reinterpret_cast<const float4*>(&Psm[t][i0]);
          s0 += p4.x * uu[i0 + 0]; s1 += p4.y * uu[i0 + 1];
          s2 += p4.z * uu[i0 + 2]; s3 += p4.w * uu[i0 + 3];
        }
        for (int i = ((t + 1) >> 2) << 2; i <= t; ++i) s0 += Psm[t][i] * uu[i];
        qsa[t][cB] = o + (s0 + s1) + (s2 + s3);
      }
    }
    __syncthreads();

    // write O tile (coalesced float4)
    {
      int row = tid >> 2, c4 = (tid & 3) * 4;
      float4 o4 = make_float4(qsa[row][c4 + 0], qsa[row][c4 + 1],
                              qsa[row][c4 + 2], qsa[row][c4 + 3]);
      *reinterpret_cast<float4*>(&Of[(base + row) * 1024 + c0 + c4]) = o4;
    }

    // ---- phase C: S_c += u^T K ----
    for (int d0 = 0; d0 < 1024; d0 += 64) {
      __syncthreads();
#pragma unroll
      for (int i = 0; i < 4; ++i) {
        int idx = tid + i * 256;
        int row = idx >> 4, d4 = (idx & 15) * 4;
        *reinterpret_cast<float4*>(&Ksm[row][d4]) =
            *reinterpret_cast<const float4*>(&Kf[(base + row) * 1024 + d0 + d4]);
      }
      __syncthreads();
      {
        const int cC = tid & 15;
        const int dloc = (tid >> 4) * 4;
        float4 s4 = *reinterpret_cast<const float4*>(&Ssl[cC][d0 + dloc]);
#pragma unroll
        for (int t = 0; t < 64; t += 4) {
          float4 u4 = *reinterpret_cast<const float4*>(&uT[cC][t]);
          float4 k0 = *reinterpret_cast<const float4*>(&Ksm[t + 0][dloc]);
          float4 k1 = *reinterpret_cast<const float4*>(&Ksm[t + 1][dloc]);
          float4 k2 = *reinterpret_cast<const float4*>(&Ksm[t + 2][dloc]);
          float4 k3 = *reinterpret_cast<const float4*>(&Ksm[t + 3][dloc]);
          s4.x += u4.x * k0.x + u4.y * k1.x + u4.z * k2.x + u4.w * k3.x;
          s4.y += u4.x * k0.y + u4.y * k1.y + u4.z * k2.y + u4.w * k3.y;
          s4.z += u4.x * k0.z + u4.y * k1.z + u4.z * k2.z + u4.w * k3.z;
          s4.w += u4.x * k0.w + u4.y * k1.w + u4.z * k2.w + u4.w * k3.w;
        }
        *reinterpret_cast<float4*>(&Ssl[cC][d0 + dloc]) = s4;
      }
    }
    __syncthreads();
  }

  // spill S slice for next group
  if (g < ngrp - 1) {
#pragma unroll
    for (int i = 0; i < 16; ++i) {
      int idx = tid + i * 256;
      int r = idx >> 8, d4 = (idx & 255) * 4;
      *reinterpret_cast<float4*>(&Sglob[((size_t)b * 1024 + c0 + r) * 1024 + d4]) =
          *reinterpret_cast<const float4*>(&Ssl[r][d4]);
    }
  }
}

// ---------------------------------------------------------------------------
extern "C" void kernel_launch(void* const* d_in, const int* in_sizes, int n_in,
                              void* d_out, int out_size, void* d_ws, size_t ws_size,
                              hipStream_t stream) {
  const float* x  = (const float*)d_in[0];
  const float* Wq = (const float*)d_in[1];
  const float* Wk = (const float*)d_in[2];
  const float* Wv = (const float*)d_in[3];
  const float* Wo = (const float*)d_in[4];
  float* out = (float*)d_out;

  // tier: largest time-group that fits ws
  int lsh = 8;
  {
    const int cand[4] = {11, 10, 9, 8};
    for (int i = 0; i < 4; ++i) {
      size_t tgs = (size_t)1 << cand[i];
      size_t cpg = tgs / CH;
      size_t need = 4 * (B_ * tgs * 1024 * 4)             // Q,K,V,O
                  + 2 * (cpg * B_ * CH * 64 * 4)          // A,P
                  + (size_t)B_ * 1024 * 1024 * 4          // Sglob
                  + 16384;
      if (need <= ws_size) { lsh = cand[i]; break; }
    }
  }
  const int tgs = 1 << lsh;
  const int cpg = tgs / CH;
  const int ngrp = T_ / tgs;
  const int rows = B_ * tgs;

  char* ws = (char*)d_ws;
  size_t off = 0;
  auto alloc = [&](size_t bytes) -> void* {
    void* p = ws + off;
    off += (bytes + 255) & ~(size_t)255;
    return p;
  };
  float* Qg = (float*)alloc((size_t)rows * 1024 * 4);
  float* Kg = (float*)alloc((size_t)rows * 1024 * 4);
  float* Vg = (float*)alloc((size_t)rows * 1024 * 4);
  float* Og = (float*)alloc((size_t)rows * 1024 * 4);
  float* Ag = (float*)alloc((size_t)cpg * B_ * CH * 64 * 4);
  float* Pg = (float*)alloc((size_t)cpg * B_ * CH * 64 * 4);
  float* Sglob = (float*)alloc((size_t)B_ * 1024 * 1024 * 4);

  for (int g = 0; g < ngrp; ++g) {
    int tg = g * tgs;
    gemm_qkv<<<dim3(rows / 128, 8, 3), 256, 0, stream>>>(x, Wq, Wk, Wv, Qg, Kg, Vg, tg, lsh);
    knorm_kernel<<<rows, 256, 0, stream>>>(Kg);
    attn_all_kernel<<<dim3(2, B_, cpg), 256, 0, stream>>>(Qg, Kg, Ag, Pg, tgs);
    chain_kernel<<<256, 256, 0, stream>>>(Qg, Kg, Vg, Og, Ag, Pg, Sglob, lsh, cpg, g, ngrp);
    gemm_out<<<dim3(rows / 128, 8), 256, 0, stream>>>(Og, Wo, out, tg, lsh);
  }
}